// Round 2
// 554.465 us; speedup vs baseline: 1.0631x; 1.0631x over previous
//
#include <hip/hip_runtime.h>
#include <hip/hip_bf16.h>
#include <math.h>

// Problem dims
#define CC 128          // C
#define DI 256          // D_INNER
#define SSEQ 256        // B*N sequences
#define ROWS 65536      // SSEQ*TT

typedef __hip_bfloat16 bf16;
typedef __attribute__((ext_vector_type(8))) short short8;   // 8 bf16 (4 VGPRs) MFMA A/B frag
typedef __attribute__((ext_vector_type(4))) float float4v;  // MFMA C/D frag

__device__ __forceinline__ float to_f(float v) { return v; }
__device__ __forceinline__ float to_f(bf16 v)  { return __bfloat162float(v); }
__device__ __forceinline__ bf16  f2b(float v)  { return __float2bfloat16(v); }
__device__ __forceinline__ float bf2f_bits(short v) {
    union { unsigned u; float f; } c; c.u = ((unsigned)(unsigned short)v) << 16; return c.f;
}

__device__ __forceinline__ float wave_sum(float v) {
    #pragma unroll
    for (int o = 1; o < 64; o <<= 1) v += __shfl_xor(v, o, 64);
    return v;
}
__device__ __forceinline__ float silu_f(float x) {
    return x * __builtin_amdgcn_rcpf(1.f + __expf(-x));
}
__device__ __forceinline__ float gelu_f(float x) { return 0.5f * x * (1.f + erff(x * 0.70710678118654752f)); }
__device__ __forceinline__ float softplus_f(float x) {
    return (x > 20.f) ? x : __logf(1.f + __expf(x));
}

// ---------------- LN1: x (B,T,N,C) fp32 -> bf16 rows in (s,t) order, s = b*64+n ----------------
__global__ __launch_bounds__(256) void ln1_kernel(const float* __restrict__ x,
                                                  const float* __restrict__ g,
                                                  const float* __restrict__ b,
                                                  bf16* __restrict__ out) {
    int wave = threadIdx.x >> 6, lane = threadIdx.x & 63;
    int r = blockIdx.x * 4 + wave;
    int s = r >> 8, t = r & 255;
    int bb = s >> 6, n = s & 63;
    size_t xbase = (((size_t)(bb * 256 + t)) * 64 + n) * CC;
    float v0 = x[xbase + lane], v1 = x[xbase + lane + 64];
    float s1 = wave_sum(v0 + v1);
    float s2 = wave_sum(v0 * v0 + v1 * v1);
    float m = s1 * (1.f / 128.f);
    float var = s2 * (1.f / 128.f) - m * m;
    float rstd = rsqrtf(var + 1e-5f);
    size_t ob = (size_t)r * CC;
    out[ob + lane]      = f2b((v0 - m) * rstd * g[lane]      + b[lane]);
    out[ob + lane + 64] = f2b((v1 - m) * rstd * g[lane + 64] + b[lane + 64]);
}

// ---------------- LN3: fp32 row-major in -> bf16 out ----------------
__global__ __launch_bounds__(256) void ln3_kernel(const float* __restrict__ in,
                                                  const float* __restrict__ g,
                                                  const float* __restrict__ b,
                                                  bf16* __restrict__ out) {
    int wave = threadIdx.x >> 6, lane = threadIdx.x & 63;
    int r = blockIdx.x * 4 + wave;
    size_t ib = (size_t)r * CC;
    float v0 = in[ib + lane], v1 = in[ib + lane + 64];
    float s1 = wave_sum(v0 + v1);
    float s2 = wave_sum(v0 * v0 + v1 * v1);
    float m = s1 * (1.f / 128.f);
    float var = s2 * (1.f / 128.f) - m * m;
    float rstd = rsqrtf(var + 1e-5f);
    out[ib + lane]      = f2b((v0 - m) * rstd * g[lane]      + b[lane]);
    out[ib + lane + 64] = f2b((v1 - m) * rstd * g[lane + 64] + b[lane + 64]);
}

// ================= MFMA GEMM, 64x64 tile, 256 threads (4 waves) =================
template <bool BTR, int EPI, int KTILES>
__global__ __launch_bounds__(256) void mfma_gemm_kernel(const bf16* __restrict__ A, int lda,
                                                        const float* __restrict__ B,
                                                        const float* __restrict__ bias,
                                                        void* __restrict__ Cout, int ldc,
                                                        int N, int K) {
    __shared__ bf16 As[64][40];
    __shared__ bf16 Bs[64][40];
    int tid = threadIdx.x;
    int m0 = blockIdx.x * 64;
    int n0 = blockIdx.y * 64;
    int wv = tid >> 6, lane = tid & 63;
    int lrow = lane & 15, quad = lane >> 4;
    int lk = quad * 8;
    float4v acc[4] = {};
    #pragma unroll
    for (int kt = 0; kt < KTILES; kt++) {
        int k0 = kt * 32;
        {
            int m = tid >> 2, part = tid & 3;
            uint4 v = *(const uint4*)(A + (size_t)(m0 + m) * lda + k0 + part * 8);
            *(uint4*)&As[m][part * 8] = v;
        }
        if (BTR) {
            int n = tid >> 2, part = tid & 3;
            const float* src = B + (size_t)(n0 + n) * K + k0 + part * 8;
            bf16 tmp[8];
            #pragma unroll
            for (int j = 0; j < 8; j++) tmp[j] = f2b(src[j]);
            *(uint4*)&Bs[n][part * 8] = *(uint4*)tmp;
        } else {
            int kk = tid >> 3, nf = (tid & 7) * 8;
            const float* src = B + (size_t)(k0 + kk) * N + n0 + nf;
            #pragma unroll
            for (int j = 0; j < 8; j++) Bs[nf + j][kk] = f2b(src[j]);
        }
        __syncthreads();
        short8 a = *(const short8*)&As[wv * 16 + lrow][lk];
        #pragma unroll
        for (int jt = 0; jt < 4; jt++) {
            short8 bfr = *(const short8*)&Bs[jt * 16 + lrow][lk];
            acc[jt] = __builtin_amdgcn_mfma_f32_16x16x32_bf16(a, bfr, acc[jt], 0, 0, 0);
        }
        __syncthreads();
    }
    #pragma unroll
    for (int jt = 0; jt < 4; jt++) {
        int col = n0 + jt * 16 + lrow;
        float bs = (EPI >= 1) ? bias[col] : 0.f;
        #pragma unroll
        for (int r = 0; r < 4; r++) {
            int row = m0 + wv * 16 + quad * 4 + r;
            float v = acc[jt][r] + bs;
            if (EPI == 1) v = gelu_f(v);
            if (EPI == 2) {
                float* Cf = (float*)Cout;
                Cf[(size_t)row * ldc + col] += v;
            } else {
                bf16* Cb = (bf16*)Cout;
                Cb[(size_t)row * ldc + col] = f2b(v);
            }
        }
    }
}

// ======== MFMA W_out GEMM (64x128 tile), A = (YF+YB)*silu(z), fused LN2 + residual ========
__global__ __launch_bounds__(256) void mfma_ln2res_kernel(const bf16* __restrict__ YF,
                                                          const bf16* __restrict__ YB,
                                                          const bf16* __restrict__ xz,
                                                          const float* __restrict__ Wout,
                                                          const float* __restrict__ g,
                                                          const float* __restrict__ b,
                                                          const float* __restrict__ x,
                                                          float* __restrict__ out) {
    __shared__ bf16 As[64][40];
    __shared__ bf16 Bs[128][40];
    int tid = threadIdx.x;
    int m0 = blockIdx.x * 64;
    int wv = tid >> 6, lane = tid & 63;
    int lrow = lane & 15, quad = lane >> 4;
    int lk = quad * 8;
    float4v acc[8] = {};
    #pragma unroll
    for (int kt = 0; kt < 8; kt++) {          // K = 256
        int k0 = kt * 32;
        {
            int m = tid >> 2, part = tid & 3;
            size_t off = (size_t)(m0 + m) * 256 + k0 + part * 8;
            short8 vf = *(const short8*)(YF + off);
            short8 vb = *(const short8*)(YB + off);
            short8 vz = *(const short8*)(xz + (size_t)(m0 + m) * 512 + 256 + k0 + part * 8);
            bf16 tmp[8];
            #pragma unroll
            for (int j = 0; j < 8; j++)
                tmp[j] = f2b((bf2f_bits(vf[j]) + bf2f_bits(vb[j])) * silu_f(bf2f_bits(vz[j])));
            *(uint4*)&As[m][part * 8] = *(uint4*)tmp;
        }
        #pragma unroll
        for (int it = 0; it < 2; it++) {
            int idx = tid + it * 256;
            int n = idx >> 2, part = idx & 3;
            const float* src = Wout + (size_t)n * 256 + k0 + part * 8;
            bf16 tmp[8];
            #pragma unroll
            for (int j = 0; j < 8; j++) tmp[j] = f2b(src[j]);
            *(uint4*)&Bs[n][part * 8] = *(uint4*)tmp;
        }
        __syncthreads();
        short8 a = *(const short8*)&As[wv * 16 + lrow][lk];
        #pragma unroll
        for (int jt = 0; jt < 8; jt++) {
            short8 bfr = *(const short8*)&Bs[jt * 16 + lrow][lk];
            acc[jt] = __builtin_amdgcn_mfma_f32_16x16x32_bf16(a, bfr, acc[jt], 0, 0, 0);
        }
        __syncthreads();
    }
    #pragma unroll
    for (int r = 0; r < 4; r++) {
        float ps = 0.f, ps2 = 0.f;
        #pragma unroll
        for (int jt = 0; jt < 8; jt++) { float v = acc[jt][r]; ps += v; ps2 += v * v; }
        #pragma unroll
        for (int o = 1; o < 16; o <<= 1) {
            ps  += __shfl_xor(ps, o, 64);
            ps2 += __shfl_xor(ps2, o, 64);
        }
        float m = ps * (1.f / 128.f);
        float var = ps2 * (1.f / 128.f) - m * m;
        float rstd = rsqrtf(var + 1e-5f);
        int row = m0 + wv * 16 + quad * 4 + r;
        int s = row >> 8, t = row & 255;
        int bb = s >> 6, n = s & 63;
        size_t xbase = (((size_t)(bb * 256 + t)) * 64 + n) * CC;
        #pragma unroll
        for (int jt = 0; jt < 8; jt++) {
            int col = jt * 16 + lrow;
            out[xbase + col] = (acc[jt][r] - m) * rstd * g[col] + b[col] + x[xbase + col];
        }
    }
}

// ======== MFMA xdbl GEMM with fused causal conv + SiLU A-staging ========
// C[s*256+t][0..40) = silu(conv(xc))[t] @ Wx.T.  Block = 64 rows of one sequence.
// Grid 1024: blockIdx = s*4 + tile (t0 = tile*64).  DIR selects time mapping.
template <int DIR>
__global__ __launch_bounds__(256) void mfma_conv_kernel(const bf16* __restrict__ xz,
                                                        const float* __restrict__ cw,
                                                        const float* __restrict__ cb,
                                                        const float* __restrict__ Wx,
                                                        bf16* __restrict__ C) {
    __shared__ bf16 As[64][40];
    __shared__ bf16 Bs[48][40];
    int tid = threadIdx.x;
    int s = blockIdx.x >> 2;
    int t0 = (blockIdx.x & 3) * 64;
    int wv = tid >> 6, lane = tid & 63;
    int lrow = lane & 15, quad = lane >> 4;
    int lk = quad * 8;
    float4v acc[3] = {};
    #pragma unroll
    for (int kt = 0; kt < 8; kt++) {          // K = 256 channels
        int k0 = kt * 32;
        // ---- A-stage: fused 4-tap conv + SiLU -> bf16, thread covers (row m, 8 channels) ----
        {
            int m = tid >> 2, part = tid & 3;
            int t = t0 + m;
            int dbase = k0 + part * 8;
            float a[8];
            float4 w4[8];
            #pragma unroll
            for (int i = 0; i < 8; i++) {
                a[i]  = cb[dbase + i];
                w4[i] = ((const float4*)cw)[dbase + i];   // cw[d][0..3]
            }
            #pragma unroll
            for (int j = 0; j < 4; j++) {
                int tj = t - 3 + j;
                if (tj >= 0) {
                    int src = DIR ? (255 - tj) : tj;
                    uint4 v = *(const uint4*)(xz + (size_t)(s * 256 + src) * 512 + dbase);
                    short8 sv = *(short8*)&v;
                    #pragma unroll
                    for (int i = 0; i < 8; i++) {
                        float w = (j == 0) ? w4[i].x : (j == 1) ? w4[i].y : (j == 2) ? w4[i].z : w4[i].w;
                        a[i] += w * bf2f_bits(sv[i]);
                    }
                }
            }
            bf16 tmp[8];
            #pragma unroll
            for (int i = 0; i < 8; i++) tmp[i] = f2b(silu_f(a[i]));
            *(uint4*)&As[m][part * 8] = *(uint4*)tmp;
        }
        // ---- B-stage: Wx [40][256] fp32 -> Bs[48][32] bf16 (rows 40-47 zero) ----
        {
            int n = tid >> 2, part = tid & 3;
            if (n < 48) {
                bf16 tmp[8];
                #pragma unroll
                for (int j = 0; j < 8; j++)
                    tmp[j] = (n < 40) ? f2b(Wx[(size_t)n * 256 + k0 + part * 8 + j]) : f2b(0.f);
                *(uint4*)&Bs[n][part * 8] = *(uint4*)tmp;
            }
        }
        __syncthreads();
        short8 a = *(const short8*)&As[wv * 16 + lrow][lk];
        #pragma unroll
        for (int jt = 0; jt < 3; jt++) {
            short8 bfr = *(const short8*)&Bs[jt * 16 + lrow][lk];
            acc[jt] = __builtin_amdgcn_mfma_f32_16x16x32_bf16(a, bfr, acc[jt], 0, 0, 0);
        }
        __syncthreads();
    }
    #pragma unroll
    for (int jt = 0; jt < 3; jt++) {
        int col = jt * 16 + lrow;
        if (col < 40) {
            #pragma unroll
            for (int r = 0; r < 4; r++) {
                int row = t0 + wv * 16 + quad * 4 + r;
                C[(size_t)(s * 256 + row) * 40 + col] = f2b(acc[jt][r]);
            }
        }
    }
}

// ---------------- Direction-parallel selective scan v4 ----------------
// Exploit A[n] = (n+1)*A[0] (A_log = log(tile(arange(1..16)))) so
// dA[n] = exp(dt*A[n]) = p^(n+1), p = exp(dt*A[0]): 1 exp + 15 muls (depth-4
// product tree) instead of 16 exps/step.  Runtime structure check with exact
// fallback to the general 16-exp path.  Software-pipelined LDS row reads
// (named double-buffer regs), 4-way split y accumulation, incremental pointers.
// NOTE: all pasted identifiers parenthesized before member access (pp-number fix).

#define LOADROW(R, T) do {                                                  \
    const float4* rp_ = (const float4*)(rows + (T) * 40);                   \
    R##0 = rp_[0]; R##1 = rp_[1]; R##2 = rp_[2]; R##3 = rp_[3];             \
    R##4 = rp_[4]; R##5 = rp_[5]; R##6 = rp_[6]; R##7 = rp_[7];             \
    R##8 = rp_[8]; R##9 = rp_[9];                                           \
} while (0)

#define SCAN_STEP(T, R) do {                                                \
    float xc_ = xc0; xc0 = xc1;                                             \
    if ((T) + 2 < 256) { xc1 = to_f(*xnext); xnext += xstep; }              \
    w0 = w1; w1 = w2; w2 = w3; w3 = xc_;                                    \
    float u_ = silu_f(cb + c0 * w0 + c1 * w1 + c2 * w2 + c3 * w3);          \
    float dtr_ = bd + (R##0).x * wdt[0] + (R##0).y * wdt[1]                 \
                    + (R##0).z * wdt[2] + (R##0).w * wdt[3]                 \
                    + (R##1).x * wdt[4] + (R##1).y * wdt[5]                 \
                    + (R##1).z * wdt[6] + (R##1).w * wdt[7];                \
    float dt_ = softplus_f(dtr_);                                           \
    float du_ = dt_ * u_;                                                   \
    float d1 = __expf(dt_ * A0);                                            \
    float d2 = d1*d1, d3 = d2*d1, d4 = d2*d2, d5 = d4*d1;                   \
    float d6 = d4*d2, d7 = d4*d3, d8 = d4*d4;                               \
    float d9 = d8*d1, d10 = d8*d2, d11 = d8*d3, d12 = d8*d4;                \
    float d13 = d8*d5, d14 = d8*d6, d15 = d8*d7, d16 = d8*d8;               \
    float y0_, y1_, y2_, y3_;                                               \
    h0  = d1  * h0  + du_ * (R##2).x; y0_  = h0  * (R##6).x;                \
    h1  = d2  * h1  + du_ * (R##2).y; y1_  = h1  * (R##6).y;                \
    h2  = d3  * h2  + du_ * (R##2).z; y2_  = h2  * (R##6).z;                \
    h3  = d4  * h3  + du_ * (R##2).w; y3_  = h3  * (R##6).w;                \
    h4  = d5  * h4  + du_ * (R##3).x; y0_ += h4  * (R##7).x;                \
    h5  = d6  * h5  + du_ * (R##3).y; y1_ += h5  * (R##7).y;                \
    h6  = d7  * h6  + du_ * (R##3).z; y2_ += h6  * (R##7).z;                \
    h7  = d8  * h7  + du_ * (R##3).w; y3_ += h7  * (R##7).w;                \
    h8  = d9  * h8  + du_ * (R##4).x; y0_ += h8  * (R##8).x;                \
    h9  = d10 * h9  + du_ * (R##4).y; y1_ += h9  * (R##8).y;                \
    h10 = d11 * h10 + du_ * (R##4).z; y2_ += h10 * (R##8).z;                \
    h11 = d12 * h11 + du_ * (R##4).w; y3_ += h11 * (R##8).w;                \
    h12 = d13 * h12 + du_ * (R##5).x; y0_ += h12 * (R##9).x;                \
    h13 = d14 * h13 + du_ * (R##5).y; y1_ += h13 * (R##9).y;                \
    h14 = d15 * h14 + du_ * (R##5).z; y2_ += h14 * (R##9).z;                \
    h15 = d16 * h15 + du_ * (R##5).w; y3_ += h15 * (R##9).w;                \
    float yv_ = (y0_ + y1_) + (y2_ + y3_) + u_ * Dd;                        \
    *yp = f2b(yv_); yp += ystep;                                            \
} while (0)

__global__ __launch_bounds__(256) void scan_kernel(const bf16* __restrict__ xz,
        const bf16* __restrict__ xdbl_f, const bf16* __restrict__ xdbl_b,
        const float* __restrict__ cw_f, const float* __restrict__ cb_f,
        const float* __restrict__ Wdt_f, const float* __restrict__ bdt_f,
        const float* __restrict__ Alog_f, const float* __restrict__ D_f,
        const float* __restrict__ cw_b, const float* __restrict__ cb_b,
        const float* __restrict__ Wdt_b, const float* __restrict__ bdt_b,
        const float* __restrict__ Alog_b, const float* __restrict__ D_b,
        bf16* __restrict__ YF, bf16* __restrict__ YB) {
    __shared__ float rows[256 * 40];   // 40 KB fp32
    int tid = threadIdx.x;
    int dir = blockIdx.x >> 8;
    int s = blockIdx.x & 255;
    int d = tid;

    const bf16* xd = (dir ? xdbl_b : xdbl_f) + (size_t)s * 10240;
    #pragma unroll
    for (int i = 0; i < 5; i++) {
        int idx = i * 256 + tid;
        uint4 v = ((const uint4*)xd)[idx];
        short8 sv = *(short8*)&v;
        float f[8];
        #pragma unroll
        for (int j = 0; j < 8; j++) f[j] = bf2f_bits(sv[j]);
        *(float4*)&rows[idx * 8]     = *(float4*)&f[0];
        *(float4*)&rows[idx * 8 + 4] = *(float4*)&f[4];
    }

    const float* Alog = dir ? Alog_b : Alog_f;
    const float* Wdtp = dir ? Wdt_b  : Wdt_f;
    const float* cwp  = dir ? cw_b   : cw_f;
    float Aarr[16], wdt[8];
    #pragma unroll
    for (int n = 0; n < 16; n++) Aarr[n] = -__expf(Alog[d * 16 + n]);
    #pragma unroll
    for (int r = 0; r < 8; r++) wdt[r] = Wdtp[d * 8 + r];
    float bd = dir ? bdt_b[d] : bdt_f[d];
    float Dd = dir ? D_b[d]   : D_f[d];
    float cb = dir ? cb_b[d]  : cb_f[d];
    float c0 = cwp[d * 4], c1 = cwp[d * 4 + 1], c2 = cwp[d * 4 + 2], c3 = cwp[d * 4 + 3];
    bf16* Y = dir ? YB : YF;
    const bf16* xcol = xz + d;

    // Structure check: A[n] == (n+1)*A[0]  (holds for A_log = log(arange(1..16)))
    float A0 = Aarr[0];
    int pw = 1;
    #pragma unroll
    for (int n = 1; n < 16; n++)
        pw &= (fabsf(Aarr[n] - (float)(n + 1) * A0) <= 1e-4f * fabsf(Aarr[n]) + 1e-6f) ? 1 : 0;
    pw = __all(pw);
    __syncthreads();

    float w0 = 0.f, w1 = 0.f, w2 = 0.f, w3 = 0.f;
    int o0 = dir ? 255 : 0, o1 = dir ? 254 : 1;
    float xc0 = to_f(xcol[(size_t)(s * 256 + o0) * 512]);
    float xc1 = to_f(xcol[(size_t)(s * 256 + o1) * 512]);

    if (pw) {
        // -------- fast path: dA via power tree, pipelined row reads --------
        float h0 = 0.f, h1 = 0.f, h2 = 0.f, h3 = 0.f, h4 = 0.f, h5 = 0.f,
              h6 = 0.f, h7 = 0.f, h8 = 0.f, h9 = 0.f, h10 = 0.f, h11 = 0.f,
              h12 = 0.f, h13 = 0.f, h14 = 0.f, h15 = 0.f;
        const bf16* xnext = xcol + (size_t)(s * 256 + (dir ? 253 : 2)) * 512;
        ptrdiff_t xstep = dir ? -512 : 512;
        bf16* yp = Y + (size_t)(s * 256 + (dir ? 255 : 0)) * 256 + d;
        ptrdiff_t ystep = dir ? -256 : 256;
        float4 ra0, ra1, ra2, ra3, ra4, ra5, ra6, ra7, ra8, ra9;
        float4 rb0, rb1, rb2, rb3, rb4, rb5, rb6, rb7, rb8, rb9;
        LOADROW(ra, 0);
        #pragma unroll 1
        for (int t = 0; t < 256; t += 2) {
            LOADROW(rb, t + 1);
            SCAN_STEP(t, ra);
            if (t + 2 < 256) LOADROW(ra, t + 2);
            SCAN_STEP(t + 1, rb);
        }
    } else {
        // -------- general fallback: original 16-exp inner loop --------
        float h[16];
        #pragma unroll
        for (int n = 0; n < 16; n++) h[n] = 0.f;
        for (int t = 0; t < 256; t++) {
            int tt = dir ? (255 - t) : t;
            float xc = xc0; xc0 = xc1;
            if (t + 2 < 256) {
                int onx = dir ? (253 - t) : (t + 2);
                xc1 = to_f(xcol[(size_t)(s * 256 + onx) * 512]);
            }
            const float* row = rows + t * 40;
            float4 q0 = *(const float4*)(row);
            float4 q1 = *(const float4*)(row + 4);
            float4 qb0 = *(const float4*)(row + 8);
            float4 qb1 = *(const float4*)(row + 12);
            float4 qb2 = *(const float4*)(row + 16);
            float4 qb3 = *(const float4*)(row + 20);
            float4 qc0 = *(const float4*)(row + 24);
            float4 qc1 = *(const float4*)(row + 28);
            float4 qc2 = *(const float4*)(row + 32);
            float4 qc3 = *(const float4*)(row + 36);
            w0 = w1; w1 = w2; w2 = w3; w3 = xc;
            float u = silu_f(cb + c0 * w0 + c1 * w1 + c2 * w2 + c3 * w3);
            float dtr = bd;
            dtr += q0.x * wdt[0] + q0.y * wdt[1] + q0.z * wdt[2] + q0.w * wdt[3];
            dtr += q1.x * wdt[4] + q1.y * wdt[5] + q1.z * wdt[6] + q1.w * wdt[7];
            float dt = softplus_f(dtr);
            float du = dt * u, y = 0.f;
            float Bm[16] = {qb0.x,qb0.y,qb0.z,qb0.w, qb1.x,qb1.y,qb1.z,qb1.w,
                            qb2.x,qb2.y,qb2.z,qb2.w, qb3.x,qb3.y,qb3.z,qb3.w};
            float Cm[16] = {qc0.x,qc0.y,qc0.z,qc0.w, qc1.x,qc1.y,qc1.z,qc1.w,
                            qc2.x,qc2.y,qc2.z,qc2.w, qc3.x,qc3.y,qc3.z,qc3.w};
            #pragma unroll
            for (int n = 0; n < 16; n++) {
                float dA = __expf(dt * Aarr[n]);
                h[n] = dA * h[n] + du * Bm[n];
                y += h[n] * Cm[n];
            }
            y += u * Dd;
            Y[(size_t)(s * 256 + tt) * 256 + d] = f2b(y);
        }
    }
}

extern "C" void kernel_launch(void* const* d_in, const int* in_sizes, int n_in,
                              void* d_out, int out_size, void* d_ws, size_t ws_size,
                              hipStream_t stream) {
    const float* x      = (const float*)d_in[0];
    const float* g1     = (const float*)d_in[1];
    const float* b1     = (const float*)d_in[2];
    const float* W_in   = (const float*)d_in[3];
    const float* conv_w = (const float*)d_in[4];
    const float* conv_b = (const float*)d_in[5];
    const float* Wx     = (const float*)d_in[6];
    const float* Wdt    = (const float*)d_in[7];
    const float* bdt    = (const float*)d_in[8];
    const float* A_log  = (const float*)d_in[9];
    const float* Dvec   = (const float*)d_in[10];
    const float* conv_wb= (const float*)d_in[11];
    const float* conv_bb= (const float*)d_in[12];
    const float* Wxb    = (const float*)d_in[13];
    const float* Wdtb   = (const float*)d_in[14];
    const float* bdtb   = (const float*)d_in[15];
    const float* A_b_log= (const float*)d_in[16];
    const float* D_b    = (const float*)d_in[17];
    const float* W_out  = (const float*)d_in[18];
    const float* g2     = (const float*)d_in[19];
    const float* b2     = (const float*)d_in[20];
    const float* g3     = (const float*)d_in[21];
    const float* b3     = (const float*)d_in[22];
    const float* W1m    = (const float*)d_in[23];
    const float* b1m    = (const float*)d_in[24];
    const float* W2m    = (const float*)d_in[25];
    const float* b2m    = (const float*)d_in[26];

    // Workspace: 128 MiB of bf16 intermediates.
    bf16* ws  = (bf16*)d_ws;
    bf16* XZ  = ws;                    // [ROWS][512] bf16 = 64 MiB  [0, 64M)
    bf16* YF  = ws + 33554432UL;       // [ROWS][256] bf16 = 32 MiB  [64M, 96M)
    bf16* YB  = ws + 50331648UL;       // [ROWS][256] bf16 = 32 MiB  [96M, 128M)
    bf16* H2  = ws;                    // overlay (XZ dead after ln2res): 16 MiB
    bf16* HID = ws + 8388608UL;        // overlay: [16M, 48M)
    float* out = (float*)d_out;        // 8,388,608 fp32 = 32 MiB
    // d_out as scratch (dead before the real fp32 write of d_out):
    bf16* LN1OUT = (bf16*)d_out;       // [ROWS][128] bf16 = 16 MiB (dead after W_in GEMM)
    bf16* XDBL_F = (bf16*)d_out;       // [ROWS][40] bf16 = 5.24 MiB
    bf16* XDBL_B = (bf16*)d_out + 2621440UL;   // ends at 10.5 MiB

    // 1. LN1 -> d_out scratch (bf16)
    ln1_kernel<<<ROWS / 4, 256, 0, stream>>>(x, g1, b1, LN1OUT);
    // 2. XZ = LN1OUT @ W_in.T  [65536 x 512]  (MFMA)
    mfma_gemm_kernel<true, 0, 4><<<dim3(ROWS / 64, 8), 256, 0, stream>>>(
        LN1OUT, CC, W_in, nullptr, XZ, 512, 512, CC);
    // 3. xdbl (fwd/bwd): MFMA GEMM with fused conv+SiLU A-staging -> d_out scratch (bf16)
    mfma_conv_kernel<0><<<SSEQ * 4, 256, 0, stream>>>(XZ, conv_w, conv_b, Wx, XDBL_F);
    mfma_conv_kernel<1><<<SSEQ * 4, 256, 0, stream>>>(XZ, conv_wb, conv_bb, Wxb, XDBL_B);
    // 4. direction-parallel scan -> YF, YB (raw y per direction)
    scan_kernel<<<512, 256, 0, stream>>>(XZ, XDBL_F, XDBL_B,
        conv_w, conv_b, Wdt, bdt, A_log, Dvec,
        conv_wb, conv_bb, Wdtb, bdtb, A_b_log, D_b, YF, YB);
    // 5. yproj = ((YF+YB)*silu(z)) @ W_out.T, fused LN2 + residual -> d_out fp32 (MFMA)
    mfma_ln2res_kernel<<<ROWS / 64, 256, 0, stream>>>(YF, YB, XZ, W_out, g2, b2, x, out);
    // 6. H2 = LN3(xo) -> ws (XZ dead)
    ln3_kernel<<<ROWS / 4, 256, 0, stream>>>(out, g3, b3, H2);
    // 7. HID = gelu(H2 @ W1m + b1m)  [65536 x 256]  (MFMA)
    mfma_gemm_kernel<false, 1, 4><<<dim3(ROWS / 64, 4), 256, 0, stream>>>(
        H2, CC, W1m, b1m, HID, 2 * CC, 2 * CC, CC);
    // 8. d_out += HID @ W2m + b2m  (MFMA, fp32 accumulate)
    mfma_gemm_kernel<false, 2, 8><<<dim3(ROWS / 64, 2), 256, 0, stream>>>(
        HID, 2 * CC, W2m, b2m, out, CC, CC, 2 * CC);
}

// Round 3
// 522.723 us; speedup vs baseline: 1.1277x; 1.0607x over previous
//
#include <hip/hip_runtime.h>
#include <hip/hip_bf16.h>
#include <math.h>

// Problem dims
#define CC 128          // C
#define DI 256          // D_INNER
#define SSEQ 256        // B*N sequences
#define ROWS 65536      // SSEQ*TT

typedef __hip_bfloat16 bf16;
typedef __attribute__((ext_vector_type(8))) short short8;   // 8 bf16 (4 VGPRs) MFMA A/B frag
typedef __attribute__((ext_vector_type(4))) float float4v;  // MFMA C/D frag
typedef __attribute__((ext_vector_type(2))) float f32x2;    // packed fp32 (v_pk_*)

__device__ __forceinline__ float to_f(float v) { return v; }
__device__ __forceinline__ float to_f(bf16 v)  { return __bfloat162float(v); }
__device__ __forceinline__ bf16  f2b(float v)  { return __float2bfloat16(v); }
__device__ __forceinline__ float bf2f_bits(short v) {
    union { unsigned u; float f; } c; c.u = ((unsigned)(unsigned short)v) << 16; return c.f;
}
__device__ __forceinline__ f32x2 mk2(float a, float b) { f32x2 r; r.x = a; r.y = b; return r; }
__device__ __forceinline__ f32x2 fma2(f32x2 a, f32x2 b, f32x2 c) { return a * b + c; }

__device__ __forceinline__ float wave_sum(float v) {
    #pragma unroll
    for (int o = 1; o < 64; o <<= 1) v += __shfl_xor(v, o, 64);
    return v;
}
__device__ __forceinline__ float silu_f(float x) {
    return x * __builtin_amdgcn_rcpf(1.f + __expf(-x));
}
__device__ __forceinline__ float gelu_f(float x) { return 0.5f * x * (1.f + erff(x * 0.70710678118654752f)); }
__device__ __forceinline__ float softplus_f(float x) {
    return (x > 20.f) ? x : __logf(1.f + __expf(x));
}

// ---------------- LN1: x (B,T,N,C) fp32 -> bf16 rows in (s,t) order, s = b*64+n ----------------
__global__ __launch_bounds__(256) void ln1_kernel(const float* __restrict__ x,
                                                  const float* __restrict__ g,
                                                  const float* __restrict__ b,
                                                  bf16* __restrict__ out) {
    int wave = threadIdx.x >> 6, lane = threadIdx.x & 63;
    int r = blockIdx.x * 4 + wave;
    int s = r >> 8, t = r & 255;
    int bb = s >> 6, n = s & 63;
    size_t xbase = (((size_t)(bb * 256 + t)) * 64 + n) * CC;
    float v0 = x[xbase + lane], v1 = x[xbase + lane + 64];
    float s1 = wave_sum(v0 + v1);
    float s2 = wave_sum(v0 * v0 + v1 * v1);
    float m = s1 * (1.f / 128.f);
    float var = s2 * (1.f / 128.f) - m * m;
    float rstd = rsqrtf(var + 1e-5f);
    size_t ob = (size_t)r * CC;
    out[ob + lane]      = f2b((v0 - m) * rstd * g[lane]      + b[lane]);
    out[ob + lane + 64] = f2b((v1 - m) * rstd * g[lane + 64] + b[lane + 64]);
}

// ---------------- LN3: fp32 row-major in -> bf16 out ----------------
__global__ __launch_bounds__(256) void ln3_kernel(const float* __restrict__ in,
                                                  const float* __restrict__ g,
                                                  const float* __restrict__ b,
                                                  bf16* __restrict__ out) {
    int wave = threadIdx.x >> 6, lane = threadIdx.x & 63;
    int r = blockIdx.x * 4 + wave;
    size_t ib = (size_t)r * CC;
    float v0 = in[ib + lane], v1 = in[ib + lane + 64];
    float s1 = wave_sum(v0 + v1);
    float s2 = wave_sum(v0 * v0 + v1 * v1);
    float m = s1 * (1.f / 128.f);
    float var = s2 * (1.f / 128.f) - m * m;
    float rstd = rsqrtf(var + 1e-5f);
    out[ib + lane]      = f2b((v0 - m) * rstd * g[lane]      + b[lane]);
    out[ib + lane + 64] = f2b((v1 - m) * rstd * g[lane + 64] + b[lane + 64]);
}

// ================= MFMA GEMM, 64x64 tile, 256 threads (4 waves) =================
template <bool BTR, int EPI, int KTILES>
__global__ __launch_bounds__(256) void mfma_gemm_kernel(const bf16* __restrict__ A, int lda,
                                                        const float* __restrict__ B,
                                                        const float* __restrict__ bias,
                                                        void* __restrict__ Cout, int ldc,
                                                        int N, int K) {
    __shared__ bf16 As[64][40];
    __shared__ bf16 Bs[64][40];
    int tid = threadIdx.x;
    int m0 = blockIdx.x * 64;
    int n0 = blockIdx.y * 64;
    int wv = tid >> 6, lane = tid & 63;
    int lrow = lane & 15, quad = lane >> 4;
    int lk = quad * 8;
    float4v acc[4] = {};
    #pragma unroll
    for (int kt = 0; kt < KTILES; kt++) {
        int k0 = kt * 32;
        {
            int m = tid >> 2, part = tid & 3;
            uint4 v = *(const uint4*)(A + (size_t)(m0 + m) * lda + k0 + part * 8);
            *(uint4*)&As[m][part * 8] = v;
        }
        if (BTR) {
            int n = tid >> 2, part = tid & 3;
            const float* src = B + (size_t)(n0 + n) * K + k0 + part * 8;
            bf16 tmp[8];
            #pragma unroll
            for (int j = 0; j < 8; j++) tmp[j] = f2b(src[j]);
            *(uint4*)&Bs[n][part * 8] = *(uint4*)tmp;
        } else {
            int kk = tid >> 3, nf = (tid & 7) * 8;
            const float* src = B + (size_t)(k0 + kk) * N + n0 + nf;
            #pragma unroll
            for (int j = 0; j < 8; j++) Bs[nf + j][kk] = f2b(src[j]);
        }
        __syncthreads();
        short8 a = *(const short8*)&As[wv * 16 + lrow][lk];
        #pragma unroll
        for (int jt = 0; jt < 4; jt++) {
            short8 bfr = *(const short8*)&Bs[jt * 16 + lrow][lk];
            acc[jt] = __builtin_amdgcn_mfma_f32_16x16x32_bf16(a, bfr, acc[jt], 0, 0, 0);
        }
        __syncthreads();
    }
    #pragma unroll
    for (int jt = 0; jt < 4; jt++) {
        int col = n0 + jt * 16 + lrow;
        float bs = (EPI >= 1) ? bias[col] : 0.f;
        #pragma unroll
        for (int r = 0; r < 4; r++) {
            int row = m0 + wv * 16 + quad * 4 + r;
            float v = acc[jt][r] + bs;
            if (EPI == 1) v = gelu_f(v);
            if (EPI == 2) {
                float* Cf = (float*)Cout;
                Cf[(size_t)row * ldc + col] += v;
            } else {
                bf16* Cb = (bf16*)Cout;
                Cb[(size_t)row * ldc + col] = f2b(v);
            }
        }
    }
}

// ======== MFMA W_out GEMM (64x128 tile), A = (YF+YB)*silu(z), fused LN2 + residual ========
__global__ __launch_bounds__(256) void mfma_ln2res_kernel(const bf16* __restrict__ YF,
                                                          const bf16* __restrict__ YB,
                                                          const bf16* __restrict__ xz,
                                                          const float* __restrict__ Wout,
                                                          const float* __restrict__ g,
                                                          const float* __restrict__ b,
                                                          const float* __restrict__ x,
                                                          float* __restrict__ out) {
    __shared__ bf16 As[64][40];
    __shared__ bf16 Bs[128][40];
    int tid = threadIdx.x;
    int m0 = blockIdx.x * 64;
    int wv = tid >> 6, lane = tid & 63;
    int lrow = lane & 15, quad = lane >> 4;
    int lk = quad * 8;
    float4v acc[8] = {};
    #pragma unroll
    for (int kt = 0; kt < 8; kt++) {          // K = 256
        int k0 = kt * 32;
        {
            int m = tid >> 2, part = tid & 3;
            size_t off = (size_t)(m0 + m) * 256 + k0 + part * 8;
            short8 vf = *(const short8*)(YF + off);
            short8 vb = *(const short8*)(YB + off);
            short8 vz = *(const short8*)(xz + (size_t)(m0 + m) * 512 + 256 + k0 + part * 8);
            bf16 tmp[8];
            #pragma unroll
            for (int j = 0; j < 8; j++)
                tmp[j] = f2b((bf2f_bits(vf[j]) + bf2f_bits(vb[j])) * silu_f(bf2f_bits(vz[j])));
            *(uint4*)&As[m][part * 8] = *(uint4*)tmp;
        }
        #pragma unroll
        for (int it = 0; it < 2; it++) {
            int idx = tid + it * 256;
            int n = idx >> 2, part = idx & 3;
            const float* src = Wout + (size_t)n * 256 + k0 + part * 8;
            bf16 tmp[8];
            #pragma unroll
            for (int j = 0; j < 8; j++) tmp[j] = f2b(src[j]);
            *(uint4*)&Bs[n][part * 8] = *(uint4*)tmp;
        }
        __syncthreads();
        short8 a = *(const short8*)&As[wv * 16 + lrow][lk];
        #pragma unroll
        for (int jt = 0; jt < 8; jt++) {
            short8 bfr = *(const short8*)&Bs[jt * 16 + lrow][lk];
            acc[jt] = __builtin_amdgcn_mfma_f32_16x16x32_bf16(a, bfr, acc[jt], 0, 0, 0);
        }
        __syncthreads();
    }
    #pragma unroll
    for (int r = 0; r < 4; r++) {
        float ps = 0.f, ps2 = 0.f;
        #pragma unroll
        for (int jt = 0; jt < 8; jt++) { float v = acc[jt][r]; ps += v; ps2 += v * v; }
        #pragma unroll
        for (int o = 1; o < 16; o <<= 1) {
            ps  += __shfl_xor(ps, o, 64);
            ps2 += __shfl_xor(ps2, o, 64);
        }
        float m = ps * (1.f / 128.f);
        float var = ps2 * (1.f / 128.f) - m * m;
        float rstd = rsqrtf(var + 1e-5f);
        int row = m0 + wv * 16 + quad * 4 + r;
        int s = row >> 8, t = row & 255;
        int bb = s >> 6, n = s & 63;
        size_t xbase = (((size_t)(bb * 256 + t)) * 64 + n) * CC;
        #pragma unroll
        for (int jt = 0; jt < 8; jt++) {
            int col = jt * 16 + lrow;
            out[xbase + col] = (acc[jt][r] - m) * rstd * g[col] + b[col] + x[xbase + col];
        }
    }
}

// ======== MFMA xdbl GEMM with fused causal conv + SiLU A-staging ========
// C[s*256+t][0..40) = silu(conv(xc))[t] @ Wx.T.  Block = 64 rows of one sequence.
// Grid 1024: blockIdx = s*4 + tile (t0 = tile*64).  DIR selects time mapping.
// NEW: also stores u = silu(conv(xc)) (the As tiles) to U as bf16 for the scan.
// DIR=1 stores u at the time-REVERSED position so the scan's same-address
// read(u)-then-write(y) ordering is hazard-free.
template <int DIR>
__global__ __launch_bounds__(256) void mfma_conv_kernel(const bf16* __restrict__ xz,
                                                        const float* __restrict__ cw,
                                                        const float* __restrict__ cb,
                                                        const float* __restrict__ Wx,
                                                        bf16* __restrict__ C,
                                                        bf16* __restrict__ U) {
    __shared__ bf16 As[64][40];
    __shared__ bf16 Bs[48][40];
    int tid = threadIdx.x;
    int s = blockIdx.x >> 2;
    int t0 = (blockIdx.x & 3) * 64;
    int wv = tid >> 6, lane = tid & 63;
    int lrow = lane & 15, quad = lane >> 4;
    int lk = quad * 8;
    float4v acc[3] = {};
    #pragma unroll
    for (int kt = 0; kt < 8; kt++) {          // K = 256 channels
        int k0 = kt * 32;
        // ---- A-stage: fused 4-tap conv + SiLU -> bf16, thread covers (row m, 8 channels) ----
        {
            int m = tid >> 2, part = tid & 3;
            int t = t0 + m;
            int dbase = k0 + part * 8;
            float a[8];
            float4 w4[8];
            #pragma unroll
            for (int i = 0; i < 8; i++) {
                a[i]  = cb[dbase + i];
                w4[i] = ((const float4*)cw)[dbase + i];   // cw[d][0..3]
            }
            #pragma unroll
            for (int j = 0; j < 4; j++) {
                int tj = t - 3 + j;
                if (tj >= 0) {
                    int src = DIR ? (255 - tj) : tj;
                    uint4 v = *(const uint4*)(xz + (size_t)(s * 256 + src) * 512 + dbase);
                    short8 sv = *(short8*)&v;
                    #pragma unroll
                    for (int i = 0; i < 8; i++) {
                        float w = (j == 0) ? w4[i].x : (j == 1) ? w4[i].y : (j == 2) ? w4[i].z : w4[i].w;
                        a[i] += w * bf2f_bits(sv[i]);
                    }
                }
            }
            bf16 tmp[8];
            #pragma unroll
            for (int i = 0; i < 8; i++) tmp[i] = f2b(silu_f(a[i]));
            *(uint4*)&As[m][part * 8] = *(uint4*)tmp;
            // store u for the scan (time-reversed for DIR=1)
            int tu = DIR ? (255 - t) : t;
            *(uint4*)&U[((size_t)(s * 256 + tu)) * 256 + dbase] = *(uint4*)tmp;
        }
        // ---- B-stage: Wx [40][256] fp32 -> Bs[48][32] bf16 (rows 40-47 zero) ----
        {
            int n = tid >> 2, part = tid & 3;
            if (n < 48) {
                bf16 tmp[8];
                #pragma unroll
                for (int j = 0; j < 8; j++)
                    tmp[j] = (n < 40) ? f2b(Wx[(size_t)n * 256 + k0 + part * 8 + j]) : f2b(0.f);
                *(uint4*)&Bs[n][part * 8] = *(uint4*)tmp;
            }
        }
        __syncthreads();
        short8 a = *(const short8*)&As[wv * 16 + lrow][lk];
        #pragma unroll
        for (int jt = 0; jt < 3; jt++) {
            short8 bfr = *(const short8*)&Bs[jt * 16 + lrow][lk];
            acc[jt] = __builtin_amdgcn_mfma_f32_16x16x32_bf16(a, bfr, acc[jt], 0, 0, 0);
        }
        __syncthreads();
    }
    #pragma unroll
    for (int jt = 0; jt < 3; jt++) {
        int col = jt * 16 + lrow;
        if (col < 40) {
            #pragma unroll
            for (int r = 0; r < 4; r++) {
                int row = t0 + wv * 16 + quad * 4 + r;
                C[(size_t)(s * 256 + row) * 40 + col] = f2b(acc[jt][r]);
            }
        }
    }
}

// ---------------- Direction-parallel selective scan v5 ----------------
// Changes vs v4:
//  * u = silu(conv(xc)) is PRECOMPUTED by mfma_conv_kernel and stored (bf16) in
//    Y's buffer at the same (t,d) address the scan later writes y to — the scan
//    reads u then overwrites it in the same step (read-before-write, same
//    thread).  Removes the conv/silu math AND the uncoalesced 1KiB-stride xc
//    column gather from the step.
//  * fp32 pair packing (ext_vector_type(2)) for dt-dot, power tree, h update
//    and y accumulation -> v_pk_fma_f32 / v_pk_mul_f32 halve the issue count.

#define LOADROW(R, T) do {                                                  \
    const float4* rp_ = (const float4*)(rows + (T) * 40);                   \
    R##0 = rp_[0]; R##1 = rp_[1]; R##2 = rp_[2]; R##3 = rp_[3];             \
    R##4 = rp_[4]; R##5 = rp_[5]; R##6 = rp_[6]; R##7 = rp_[7];             \
    R##8 = rp_[8]; R##9 = rp_[9];                                           \
} while (0)

#define SCAN_STEP(T, R) do {                                                \
    float u_ = uc0; uc0 = uc1;                                              \
    if ((T) + 2 < 256) { uc1 = to_f(*unext); unext += ystep; }              \
    f32x2 acc2 = mk2((R##0).x, (R##0).y) * wdt01;                           \
    acc2 = fma2(mk2((R##0).z, (R##0).w), wdt23, acc2);                      \
    acc2 = fma2(mk2((R##1).x, (R##1).y), wdt45, acc2);                      \
    acc2 = fma2(mk2((R##1).z, (R##1).w), wdt67, acc2);                      \
    float dtr_ = bd + acc2.x + acc2.y;                                      \
    float dt_ = softplus_f(dtr_);                                           \
    float du_ = dt_ * u_;                                                   \
    float d1 = __expf(dt_ * A0);                                            \
    float d2v = d1 * d1;                                                    \
    f32x2 pw0 = mk2(d1, d2v);                                               \
    f32x2 dd2 = mk2(d2v, d2v);                                              \
    f32x2 pw1 = pw0 * dd2, pw2 = pw1 * dd2, pw3 = pw2 * dd2;                \
    f32x2 dd8 = mk2(pw3.y, pw3.y);                                          \
    f32x2 pw4 = pw0 * dd8, pw5 = pw1 * dd8, pw6 = pw2 * dd8, pw7 = pw3 * dd8; \
    f32x2 du2 = mk2(du_, du_);                                              \
    hp0 = fma2(pw0, hp0, du2 * mk2((R##2).x, (R##2).y));                    \
    hp1 = fma2(pw1, hp1, du2 * mk2((R##2).z, (R##2).w));                    \
    hp2 = fma2(pw2, hp2, du2 * mk2((R##3).x, (R##3).y));                    \
    hp3 = fma2(pw3, hp3, du2 * mk2((R##3).z, (R##3).w));                    \
    hp4 = fma2(pw4, hp4, du2 * mk2((R##4).x, (R##4).y));                    \
    hp5 = fma2(pw5, hp5, du2 * mk2((R##4).z, (R##4).w));                    \
    hp6 = fma2(pw6, hp6, du2 * mk2((R##5).x, (R##5).y));                    \
    hp7 = fma2(pw7, hp7, du2 * mk2((R##5).z, (R##5).w));                    \
    f32x2 ya = hp0 * mk2((R##6).x, (R##6).y);                               \
    f32x2 yb = hp1 * mk2((R##6).z, (R##6).w);                               \
    ya = fma2(hp2, mk2((R##7).x, (R##7).y), ya);                            \
    yb = fma2(hp3, mk2((R##7).z, (R##7).w), yb);                            \
    ya = fma2(hp4, mk2((R##8).x, (R##8).y), ya);                            \
    yb = fma2(hp5, mk2((R##8).z, (R##8).w), yb);                            \
    ya = fma2(hp6, mk2((R##9).x, (R##9).y), ya);                            \
    yb = fma2(hp7, mk2((R##9).z, (R##9).w), yb);                            \
    f32x2 ys = ya + yb;                                                     \
    float yv_ = ys.x + ys.y + u_ * Dd;                                      \
    *yp = f2b(yv_); yp += ystep;                                            \
} while (0)

__global__ __launch_bounds__(256) void scan_kernel(
        const bf16* __restrict__ xdbl_f, const bf16* __restrict__ xdbl_b,
        const float* __restrict__ Wdt_f, const float* __restrict__ bdt_f,
        const float* __restrict__ Alog_f, const float* __restrict__ D_f,
        const float* __restrict__ Wdt_b, const float* __restrict__ bdt_b,
        const float* __restrict__ Alog_b, const float* __restrict__ D_b,
        bf16* __restrict__ YF, bf16* __restrict__ YB) {
    __shared__ float rows[256 * 40];   // 40 KB fp32
    int tid = threadIdx.x;
    int dir = blockIdx.x >> 8;
    int s = blockIdx.x & 255;
    int d = tid;

    const bf16* xd = (dir ? xdbl_b : xdbl_f) + (size_t)s * 10240;
    #pragma unroll
    for (int i = 0; i < 5; i++) {
        int idx = i * 256 + tid;
        uint4 v = ((const uint4*)xd)[idx];
        short8 sv = *(short8*)&v;
        float f[8];
        #pragma unroll
        for (int j = 0; j < 8; j++) f[j] = bf2f_bits(sv[j]);
        *(float4*)&rows[idx * 8]     = *(float4*)&f[0];
        *(float4*)&rows[idx * 8 + 4] = *(float4*)&f[4];
    }

    const float* Alog = dir ? Alog_b : Alog_f;
    const float* Wdtp = dir ? Wdt_b  : Wdt_f;
    float Aarr[16];
    #pragma unroll
    for (int n = 0; n < 16; n++) Aarr[n] = -__expf(Alog[d * 16 + n]);
    f32x2 wdt01 = mk2(Wdtp[d * 8 + 0], Wdtp[d * 8 + 1]);
    f32x2 wdt23 = mk2(Wdtp[d * 8 + 2], Wdtp[d * 8 + 3]);
    f32x2 wdt45 = mk2(Wdtp[d * 8 + 4], Wdtp[d * 8 + 5]);
    f32x2 wdt67 = mk2(Wdtp[d * 8 + 6], Wdtp[d * 8 + 7]);
    float bd = dir ? bdt_b[d] : bdt_f[d];
    float Dd = dir ? D_b[d]   : D_f[d];
    bf16* Y = dir ? YB : YF;

    // Structure check: A[n] == (n+1)*A[0]  (holds for A_log = log(arange(1..16)))
    float A0 = Aarr[0];
    int pw = 1;
    #pragma unroll
    for (int n = 1; n < 16; n++)
        pw &= (fabsf(Aarr[n] - (float)(n + 1) * A0) <= 1e-4f * fabsf(Aarr[n]) + 1e-6f) ? 1 : 0;
    pw = __all(pw);
    __syncthreads();

    // u pipeline: u was pre-stored by mfma_conv at the SAME address we write y
    // to (natural time order), so read-u precedes write-y per step.
    bf16* yp = Y + ((size_t)(s * 256 + (dir ? 255 : 0))) * 256 + d;
    ptrdiff_t ystep = dir ? -256 : 256;
    float uc0 = to_f(*yp);
    float uc1 = to_f(*(yp + ystep));
    const bf16* unext = yp + 2 * ystep;

    if (pw) {
        // -------- fast path: pk-packed math, dA via power tree --------
        f32x2 hp0 = {}, hp1 = {}, hp2 = {}, hp3 = {},
              hp4 = {}, hp5 = {}, hp6 = {}, hp7 = {};
        float4 ra0, ra1, ra2, ra3, ra4, ra5, ra6, ra7, ra8, ra9;
        float4 rb0, rb1, rb2, rb3, rb4, rb5, rb6, rb7, rb8, rb9;
        LOADROW(ra, 0);
        #pragma unroll 1
        for (int t = 0; t < 256; t += 2) {
            LOADROW(rb, t + 1);
            SCAN_STEP(t, ra);
            if (t + 2 < 256) LOADROW(ra, t + 2);
            SCAN_STEP(t + 1, rb);
        }
    } else {
        // -------- general fallback: 16-exp inner loop (u precomputed) --------
        float h[16];
        #pragma unroll
        for (int n = 0; n < 16; n++) h[n] = 0.f;
        for (int t = 0; t < 256; t++) {
            float u = uc0; uc0 = uc1;
            if (t + 2 < 256) { uc1 = to_f(*unext); unext += ystep; }
            const float* row = rows + t * 40;
            float4 q0 = *(const float4*)(row);
            float4 q1 = *(const float4*)(row + 4);
            float4 qb0 = *(const float4*)(row + 8);
            float4 qb1 = *(const float4*)(row + 12);
            float4 qb2 = *(const float4*)(row + 16);
            float4 qb3 = *(const float4*)(row + 20);
            float4 qc0 = *(const float4*)(row + 24);
            float4 qc1 = *(const float4*)(row + 28);
            float4 qc2 = *(const float4*)(row + 32);
            float4 qc3 = *(const float4*)(row + 36);
            float dtr = bd;
            dtr += q0.x * wdt01.x + q0.y * wdt01.y + q0.z * wdt23.x + q0.w * wdt23.y;
            dtr += q1.x * wdt45.x + q1.y * wdt45.y + q1.z * wdt67.x + q1.w * wdt67.y;
            float dt = softplus_f(dtr);
            float du = dt * u, y = 0.f;
            float Bm[16] = {qb0.x,qb0.y,qb0.z,qb0.w, qb1.x,qb1.y,qb1.z,qb1.w,
                            qb2.x,qb2.y,qb2.z,qb2.w, qb3.x,qb3.y,qb3.z,qb3.w};
            float Cm[16] = {qc0.x,qc0.y,qc0.z,qc0.w, qc1.x,qc1.y,qc1.z,qc1.w,
                            qc2.x,qc2.y,qc2.z,qc2.w, qc3.x,qc3.y,qc3.z,qc3.w};
            #pragma unroll
            for (int n = 0; n < 16; n++) {
                float dA = __expf(dt * Aarr[n]);
                h[n] = dA * h[n] + du * Bm[n];
                y += h[n] * Cm[n];
            }
            y += u * Dd;
            *yp = f2b(y); yp += ystep;
        }
    }
}

extern "C" void kernel_launch(void* const* d_in, const int* in_sizes, int n_in,
                              void* d_out, int out_size, void* d_ws, size_t ws_size,
                              hipStream_t stream) {
    const float* x      = (const float*)d_in[0];
    const float* g1     = (const float*)d_in[1];
    const float* b1     = (const float*)d_in[2];
    const float* W_in   = (const float*)d_in[3];
    const float* conv_w = (const float*)d_in[4];
    const float* conv_b = (const float*)d_in[5];
    const float* Wx     = (const float*)d_in[6];
    const float* Wdt    = (const float*)d_in[7];
    const float* bdt    = (const float*)d_in[8];
    const float* A_log  = (const float*)d_in[9];
    const float* Dvec   = (const float*)d_in[10];
    const float* conv_wb= (const float*)d_in[11];
    const float* conv_bb= (const float*)d_in[12];
    const float* Wxb    = (const float*)d_in[13];
    const float* Wdtb   = (const float*)d_in[14];
    const float* bdtb   = (const float*)d_in[15];
    const float* A_b_log= (const float*)d_in[16];
    const float* D_b    = (const float*)d_in[17];
    const float* W_out  = (const float*)d_in[18];
    const float* g2     = (const float*)d_in[19];
    const float* b2     = (const float*)d_in[20];
    const float* g3     = (const float*)d_in[21];
    const float* b3     = (const float*)d_in[22];
    const float* W1m    = (const float*)d_in[23];
    const float* b1m    = (const float*)d_in[24];
    const float* W2m    = (const float*)d_in[25];
    const float* b2m    = (const float*)d_in[26];

    // Workspace: 128 MiB of bf16 intermediates.
    bf16* ws  = (bf16*)d_ws;
    bf16* XZ  = ws;                    // [ROWS][512] bf16 = 64 MiB  [0, 64M)
    bf16* YF  = ws + 33554432UL;       // [ROWS][256] bf16 = 32 MiB  [64M, 96M)  (u_f then y_f)
    bf16* YB  = ws + 50331648UL;       // [ROWS][256] bf16 = 32 MiB  [96M, 128M) (u_b then y_b)
    bf16* H2  = ws;                    // overlay (XZ dead after ln2res): 16 MiB
    bf16* HID = ws + 8388608UL;        // overlay: [16M, 48M)
    float* out = (float*)d_out;        // 8,388,608 fp32 = 32 MiB
    // d_out as scratch (dead before the real fp32 write of d_out):
    bf16* LN1OUT = (bf16*)d_out;       // [ROWS][128] bf16 = 16 MiB (dead after W_in GEMM)
    bf16* XDBL_F = (bf16*)d_out;       // [ROWS][40] bf16 = 5.24 MiB
    bf16* XDBL_B = (bf16*)d_out + 2621440UL;   // ends at 10.5 MiB

    // 1. LN1 -> d_out scratch (bf16)
    ln1_kernel<<<ROWS / 4, 256, 0, stream>>>(x, g1, b1, LN1OUT);
    // 2. XZ = LN1OUT @ W_in.T  [65536 x 512]  (MFMA)
    mfma_gemm_kernel<true, 0, 4><<<dim3(ROWS / 64, 8), 256, 0, stream>>>(
        LN1OUT, CC, W_in, nullptr, XZ, 512, 512, CC);
    // 3. xdbl (fwd/bwd): MFMA GEMM with fused conv+SiLU A-staging; u tiles -> YF/YB
    mfma_conv_kernel<0><<<SSEQ * 4, 256, 0, stream>>>(XZ, conv_w, conv_b, Wx, XDBL_F, YF);
    mfma_conv_kernel<1><<<SSEQ * 4, 256, 0, stream>>>(XZ, conv_wb, conv_bb, Wxb, XDBL_B, YB);
    // 4. direction-parallel scan: reads u from YF/YB, overwrites with y
    scan_kernel<<<512, 256, 0, stream>>>(XDBL_F, XDBL_B,
        Wdt, bdt, A_log, Dvec, Wdtb, bdtb, A_b_log, D_b, YF, YB);
    // 5. yproj = ((YF+YB)*silu(z)) @ W_out.T, fused LN2 + residual -> d_out fp32 (MFMA)
    mfma_ln2res_kernel<<<ROWS / 64, 256, 0, stream>>>(YF, YB, XZ, W_out, g2, b2, x, out);
    // 6. H2 = LN3(xo) -> ws (XZ dead)
    ln3_kernel<<<ROWS / 4, 256, 0, stream>>>(out, g3, b3, H2);
    // 7. HID = gelu(H2 @ W1m + b1m)  [65536 x 256]  (MFMA)
    mfma_gemm_kernel<false, 1, 4><<<dim3(ROWS / 64, 4), 256, 0, stream>>>(
        H2, CC, W1m, b1m, HID, 2 * CC, 2 * CC, CC);
    // 8. d_out += HID @ W2m + b2m  (MFMA, fp32 accumulate)
    mfma_gemm_kernel<false, 2, 8><<<dim3(ROWS / 64, 2), 256, 0, stream>>>(
        HID, 2 * CC, W2m, b2m, out, CC, CC, 2 * CC);
}